// Round 5
// baseline (55.433 us; speedup 1.0000x reference)
//
#include <hip/hip_runtime.h>
#include <math.h>

typedef _Float16 f16;
typedef f16 half8 __attribute__((ext_vector_type(8)));
typedef float floatx4 __attribute__((ext_vector_type(4)));

#define NF 8
#define NH 200
#define NC 8
#define MT 3               // 16-row m-tiles per wave
#define M_BLK 48           // rows per block (1 wave)
#define SCR_W 36           // scratch row stride in halfs (72B -> all-32-bank spread)
#define FRAG 512           // halfs per packed fragment (64 lanes x 8)

// ---- d_ws byte layout ----
#define WS_QI   0          // 64 f32
#define WS_B1P  256        // 224 f32 padded bias
#define WS_B2P  1152
#define WS_B3P  2048
#define WS_WP1  3008       // f16 frag-packed [1ks][13nt][64][8]  = 13312 B
#define WS_WP2  16320      // f16 [7][13][64][8] = 93184 B
#define WS_WP3  109504     // f16 [7][13][64][8] = 93184 B
#define WS_WP4  202688     // f16 [7][1][64][8]  = 7168 B
#define WS_NEED 212000     // incl. ~2KB slack for harmless prefetch overrun

// ---------------------------------------------------------------------------
// Prep: block 0 inverts Q (Gauss-Jordan w/ pivoting; exact identity for Q=I).
// All blocks pack fp32 weights into B-fragment order:
//   dst[((ks*nkt+nt)*64+lane)*8+j] = W[nt*16+(lane&15)][ks*32+(lane>>4)*8+j]
// ---------------------------------------------------------------------------
__device__ __forceinline__ void pack_frag(const float* __restrict__ W, int Nv, int Kv,
                                          int nkt, int nks, f16* __restrict__ dst, int gid)
{
    if (gid < nks * nkt * 64) {
        const int ks    = gid / (nkt * 64);
        const int rem   = gid - ks * nkt * 64;
        const int nt    = rem >> 6;
        const int lane  = rem & 63;
        const int n     = nt * 16 + (lane & 15);
        const int kbase = ks * 32 + ((lane >> 4) * 8);
        f16 tmp[8];
#pragma unroll
        for (int j = 0; j < 8; ++j) {
            const int k = kbase + j;
            tmp[j] = (n < Nv && k < Kv) ? (f16)W[n * Kv + k] : (f16)0.0f;
        }
        *(half8*)&dst[(size_t)gid * 8] = *(const half8*)tmp;
    }
}

__global__ void prep_kernel(const float* __restrict__ Q,
                            const float* __restrict__ W1, const float* __restrict__ b1,
                            const float* __restrict__ W2, const float* __restrict__ b2,
                            const float* __restrict__ W3, const float* __restrict__ b3,
                            const float* __restrict__ W4,
                            char* __restrict__ ws)
{
    const int gid = blockIdx.x * 256 + threadIdx.x;
    pack_frag(W1, NH, NF, 13, 1, (f16*)(ws + WS_WP1), gid);
    pack_frag(W2, NH, NH, 13, 7, (f16*)(ws + WS_WP2), gid);
    pack_frag(W3, NH, NH, 13, 7, (f16*)(ws + WS_WP3), gid);
    pack_frag(W4, NC, NH, 1,  7, (f16*)(ws + WS_WP4), gid);
    if (gid < 224) {
        ((float*)(ws + WS_B1P))[gid] = (gid < NH) ? b1[gid] : 0.0f;
        ((float*)(ws + WS_B2P))[gid] = (gid < NH) ? b2[gid] : 0.0f;
        ((float*)(ws + WS_B3P))[gid] = (gid < NH) ? b3[gid] : 0.0f;
    }

    if (blockIdx.x == 0) {
        __shared__ float aug[8][16];
        __shared__ int piv;
        float* Qi = (float*)(ws + WS_QI);
        const int t  = threadIdx.x;
        const bool a = t < 128;
        const int r  = (t >> 4) & 7;
        const int c2 = t & 15;
        if (a) aug[r][c2] = (c2 < 8) ? Q[r * 8 + c2] : ((c2 - 8 == r) ? 1.0f : 0.0f);
        __syncthreads();
        for (int c = 0; c < 8; ++c) {
            if (t == 0) {
                int p = c; float best = fabsf(aug[c][c]);
                for (int rr = c + 1; rr < 8; ++rr) {
                    float v = fabsf(aug[rr][c]);
                    if (v > best) { best = v; p = rr; }
                }
                piv = p;
            }
            __syncthreads();
            const int p = piv;
            float myv = a ? aug[r][c2] : 0.0f;
            __syncthreads();
            if (a) {
                if (r == c)      aug[p][c2] = myv;
                else if (r == p) aug[c][c2] = myv;
            }
            __syncthreads();
            const float pv = aug[c][c];
            __syncthreads();
            if (a && r == c) aug[r][c2] = aug[r][c2] / pv;
            __syncthreads();
            const float fac  = (a && r != c) ? aug[r][c] : 0.0f;
            const float prow = aug[c][c2];
            __syncthreads();
            if (a) aug[r][c2] -= fac * prow;
            __syncthreads();
        }
        if (a && c2 >= 8) Qi[r * 8 + (c2 - 8)] = aug[r][c2];
    }
}

// ---------------------------------------------------------------------------
// Slab layer machinery: one wave owns 48 rows. Acts in regs (frag-packed),
// per-pass 32-col transpose through wave-private LDS scratch. bf0/bf1 thread
// a one-step-ahead prefetch chain across ks, passes, and layers.
// ---------------------------------------------------------------------------
__device__ __forceinline__ half8 ldfrag(const f16* __restrict__ p, int lane)
{
    return *(const half8*)&p[lane * 8];
}

template<int NKS>
struct Layer {
    template<int P>
    static __device__ __forceinline__ void pass(const f16* __restrict__ Wp,
        const f16* __restrict__ nextLayer, const float* __restrict__ biasP,
        const half8 (&aIn)[MT][7], half8 (&aOut)[MT][7], f16* __restrict__ scr,
        half8& bf0, half8& bf1, const int lane, const int col16, const int g4)
    {
        constexpr int NT = (P < 6) ? 2 : 1;
        const f16* nxt = (P < 6) ? (Wp + 2 * (P + 1) * FRAG) : nextLayer;

        const float bv0 = biasP[(2 * P) * 16 + col16];
        const float bv1 = (NT == 2) ? biasP[(2 * P + 1) * 16 + col16] : 0.0f;
        floatx4 a0[MT], a1[MT];
#pragma unroll
        for (int mt = 0; mt < MT; ++mt) {
            floatx4 v; v[0] = bv0; v[1] = bv0; v[2] = bv0; v[3] = bv0; a0[mt] = v;
            floatx4 w; w[0] = bv1; w[1] = bv1; w[2] = bv1; w[3] = bv1; a1[mt] = w;
        }
#pragma unroll
        for (int ks = 0; ks < NKS; ++ks) {
            half8 n0, n1;
            if (ks + 1 < NKS) {
                n0 = ldfrag(Wp + ((ks + 1) * 13 + 2 * P) * FRAG, lane);
                if (NT == 2) n1 = ldfrag(Wp + ((ks + 1) * 13 + 2 * P + 1) * FRAG, lane);
                else         n1 = bf1;
            } else {
                n0 = ldfrag(nxt, lane);
                n1 = ldfrag(nxt + FRAG, lane);
            }
#pragma unroll
            for (int mt = 0; mt < MT; ++mt) {
                a0[mt] = __builtin_amdgcn_mfma_f32_16x16x32_f16(aIn[mt][ks], bf0, a0[mt], 0, 0, 0);
                if (NT == 2)
                    a1[mt] = __builtin_amdgcn_mfma_f32_16x16x32_f16(aIn[mt][ks], bf1, a1[mt], 0, 0, 0);
            }
            bf0 = n0; bf1 = n1;
        }
        // epilogue: relu + f16, C tile (col=lane&15, row=(lane>>4)*4+r) -> scr
#pragma unroll
        for (int mt = 0; mt < MT; ++mt) {
#pragma unroll
            for (int r = 0; r < 4; ++r) {
                const int row = mt * 16 + g4 * 4 + r;
                scr[row * SCR_W + col16] = (f16)fmaxf(a0[mt][r], 0.0f);
                scr[row * SCR_W + 16 + col16] =
                    (NT == 2) ? (f16)fmaxf(a1[mt][r], 0.0f) : (f16)0.0f;
            }
        }
        // readback: next-layer A-frags for k-slot P
#pragma unroll
        for (int mt = 0; mt < MT; ++mt)
            aOut[mt][P] = *(const half8*)&scr[(mt * 16 + col16) * SCR_W + g4 * 8];
    }

    static __device__ __forceinline__ void run(const f16* __restrict__ Wp,
        const f16* __restrict__ nextLayer, const float* __restrict__ biasP,
        const half8 (&aIn)[MT][7], half8 (&aOut)[MT][7], f16* __restrict__ scr,
        half8& bf0, half8& bf1, const int lane, const int col16, const int g4)
    {
        pass<0>(Wp, nextLayer, biasP, aIn, aOut, scr, bf0, bf1, lane, col16, g4);
        pass<1>(Wp, nextLayer, biasP, aIn, aOut, scr, bf0, bf1, lane, col16, g4);
        pass<2>(Wp, nextLayer, biasP, aIn, aOut, scr, bf0, bf1, lane, col16, g4);
        pass<3>(Wp, nextLayer, biasP, aIn, aOut, scr, bf0, bf1, lane, col16, g4);
        pass<4>(Wp, nextLayer, biasP, aIn, aOut, scr, bf0, bf1, lane, col16, g4);
        pass<5>(Wp, nextLayer, biasP, aIn, aOut, scr, bf0, bf1, lane, col16, g4);
        pass<6>(Wp, nextLayer, biasP, aIn, aOut, scr, bf0, bf1, lane, col16, g4);
    }
};

// ---------------------------------------------------------------------------
// Slab kernel: 1 wave / block, 48 rows; head -> L1 -> L2 -> L3 -> L4.
// No barriers anywhere.
// ---------------------------------------------------------------------------
__global__ __launch_bounds__(64, 2)
void mlp_slab1(const float* __restrict__ x,
               const float* __restrict__ W0, const float* __restrict__ b0,
               const float* __restrict__ b4,
               const char* __restrict__ ws,
               float* __restrict__ out, int B)
{
    __shared__ f16 scr[M_BLK * SCR_W];             // 3456 B
    const int lane  = threadIdx.x & 63;
    const int col16 = lane & 15;
    const int g4    = lane >> 4;

    const float* Qi  = (const float*)(ws + WS_QI);
    const float* b1p = (const float*)(ws + WS_B1P);
    const float* b2p = (const float*)(ws + WS_B2P);
    const float* b3p = (const float*)(ws + WS_B3P);
    const f16*  Wp1  = (const f16*)(ws + WS_WP1);
    const f16*  Wp2  = (const f16*)(ws + WS_WP2);
    const f16*  Wp3  = (const f16*)(ws + WS_WP3);
    const f16*  Wp4  = (const f16*)(ws + WS_WP4);

    // start the prefetch chain (L1 pass0 frags) before any compute
    half8 bf0 = ldfrag(Wp1, lane);
    half8 bf1 = ldfrag(Wp1 + FRAG, lane);

    // ---- head: fc0 + reduced-KKT QP (fp32); lane l owns row base+l (l<48) ----
    const long g0 = (long)blockIdx.x * M_BLK + lane;
    float xr[NF];
    if (lane < M_BLK && g0 < B) {
        const float4* xp = (const float4*)(x + g0 * NF);
        const float4 A = xp[0], Bv = xp[1];
        xr[0] = A.x; xr[1] = A.y; xr[2] = A.z; xr[3] = A.w;
        xr[4] = Bv.x; xr[5] = Bv.y; xr[6] = Bv.z; xr[7] = Bv.w;
    } else {
#pragma unroll
        for (int i = 0; i < NF; ++i) xr[i] = 0.0f;
    }
    float h[NF];
#pragma unroll
    for (int j = 0; j < NF; ++j) {
        float acc = b0[j];
#pragma unroll
        for (int k = 0; k < NF; ++k) acc = fmaf(W0[j * NF + k], xr[k], acc);
        h[j] = acc;
    }
    // z = Qi h - Qi A' nu, nu = (A Qi A')^-1 (A Qi h - A h); exact z = h for Q = I
    float tq[NF], u0[NF], u1[NF];
    const float h3 = h[3];
#pragma unroll
    for (int i = 0; i < NF; ++i) {
        float s = 0.0f;
#pragma unroll
        for (int k = 0; k < NF; ++k) s = fmaf(Qi[i * NF + k], h[k], s);
        tq[i] = s;
        u0[i] = fmaf(Qi[i * NF + 4], h3, Qi[i * NF + 5]);
        u1[i] = fmaf(Qi[i * NF + 6], h3, Qi[i * NF + 7]);
    }
    const float m00 = fmaf(h3, u0[4], u0[5]);
    const float m01 = fmaf(h3, u1[4], u1[5]);
    const float m10 = fmaf(h3, u0[6], u0[7]);
    const float m11 = fmaf(h3, u1[6], u1[7]);
    const float r0  = fmaf(h3, tq[4], tq[5]) - fmaf(h3, h[4], h[5]);
    const float r1  = fmaf(h3, tq[6], tq[7]) - fmaf(h3, h[6], h[7]);
    const float idet = 1.0f / (m00 * m11 - m01 * m10);
    const float nu0 = (m11 * r0 - m01 * r1) * idet;
    const float nu1 = (m00 * r1 - m10 * r0) * idet;

    if (lane < M_BLK) {
        half8 zh, zz = {};
#pragma unroll
        for (int k = 0; k < 8; ++k) zh[k] = (f16)(tq[k] - u0[k] * nu0 - u1[k] * nu1);
        *(half8*)&scr[lane * SCR_W + 0]  = zh;   // cols 0..7 = z
        *(half8*)&scr[lane * SCR_W + 8]  = zz;   // cols 8..15 = 0
        *(half8*)&scr[lane * SCR_W + 16] = zz;   // cols 16..23 = 0
        *(half8*)&scr[lane * SCR_W + 24] = zz;   // cols 24..31 = 0
    }

    half8 aA[MT][7], aB[MT][7];
#pragma unroll
    for (int mt = 0; mt < MT; ++mt)
        aA[mt][0] = *(const half8*)&scr[(mt * 16 + col16) * SCR_W + g4 * 8];

    Layer<1>::run(Wp1, Wp2, b1p, aA, aB, scr, bf0, bf1, lane, col16, g4);  // L1
    Layer<7>::run(Wp2, Wp3, b2p, aB, aA, scr, bf0, bf1, lane, col16, g4);  // L2
    Layer<7>::run(Wp3, Wp4, b3p, aA, aB, scr, bf0, bf1, lane, col16, g4);  // L3

    // ---- L4: 200 -> 8 (bf0 already holds Wp4 ks=0 from the chain) ----
    {
        floatx4 acc4[MT];
#pragma unroll
        for (int mt = 0; mt < MT; ++mt) { floatx4 z_ = {}; acc4[mt] = z_; }
#pragma unroll
        for (int ks = 0; ks < 7; ++ks) {
            half8 n0 = (ks < 6) ? ldfrag(Wp4 + (ks + 1) * FRAG, lane) : bf0;
#pragma unroll
            for (int mt = 0; mt < MT; ++mt)
                acc4[mt] = __builtin_amdgcn_mfma_f32_16x16x32_f16(aB[mt][ks], bf0, acc4[mt], 0, 0, 0);
            bf0 = n0;
        }
        const float bias4 = b4[col16 & 7];
        const long rowbase = (long)blockIdx.x * M_BLK;
#pragma unroll
        for (int mt = 0; mt < MT; ++mt) {
#pragma unroll
            for (int r = 0; r < 4; ++r) {
                const long g = rowbase + mt * 16 + g4 * 4 + r;
                if (col16 < NC && g < B) out[g * NC + col16] = acc4[mt][r] + bias4;
            }
        }
    }
}

// ===========================================================================
// Fallback fp32 path if ws_size is too small for prep data.
// ===========================================================================
#define BT 64
#define NWAVE 8
#define JB 25
#define CH 8

__device__ __forceinline__ void layer200(const float* __restrict__ in_,
                                         float* __restrict__ out_,
                                         const float* __restrict__ W,
                                         const float* __restrict__ bias,
                                         int j0, int lane)
{
    float acc[JB];
#pragma unroll
    for (int jj = 0; jj < JB; ++jj) acc[jj] = bias[j0 + jj];
#pragma unroll 1
    for (int k0 = 0; k0 < NH; k0 += CH) {
        float a[CH];
#pragma unroll
        for (int u = 0; u < CH; ++u) a[u] = in_[(k0 + u) * BT + lane];
#pragma unroll
        for (int jj = 0; jj < JB; ++jj) {
            const float* wr = W + (j0 + jj) * NH + k0;
#pragma unroll
            for (int u = 0; u < CH; ++u) acc[jj] = fmaf(wr[u], a[u], acc[jj]);
        }
    }
#pragma unroll
    for (int jj = 0; jj < JB; ++jj)
        out_[(j0 + jj) * BT + lane] = fmaxf(acc[jj], 0.0f);
}

__global__ void qinv_kernel(const float* __restrict__ Q, float* __restrict__ Qi)
{
    __shared__ float aug[8][16];
    __shared__ int piv;
    const int t  = threadIdx.x;
    const int r  = t >> 4;
    const int c2 = t & 15;
    aug[r][c2] = (c2 < 8) ? Q[r * 8 + c2] : ((c2 - 8 == r) ? 1.0f : 0.0f);
    __syncthreads();
    for (int c = 0; c < 8; ++c) {
        if (t == 0) {
            int p = c; float best = fabsf(aug[c][c]);
            for (int rr = c + 1; rr < 8; ++rr) {
                float v = fabsf(aug[rr][c]);
                if (v > best) { best = v; p = rr; }
            }
            piv = p;
        }
        __syncthreads();
        const int p = piv;
        float myv = aug[r][c2];
        __syncthreads();
        if (r == c)      aug[p][c2] = myv;
        else if (r == p) aug[c][c2] = myv;
        __syncthreads();
        const float pv = aug[c][c];
        __syncthreads();
        if (r == c) aug[r][c2] = aug[r][c2] / pv;
        __syncthreads();
        const float fac  = (r == c) ? 0.0f : aug[r][c];
        const float prow = aug[c][c2];
        __syncthreads();
        aug[r][c2] -= fac * prow;
        __syncthreads();
    }
    if (c2 >= 8) Qi[r * 8 + (c2 - 8)] = aug[r][c2];
}

__global__ __launch_bounds__(BT * NWAVE, 2)
void mlp_fused(const float* __restrict__ x, const float* __restrict__ Qi,
               const float* __restrict__ W0, const float* __restrict__ b0,
               const float* __restrict__ W1, const float* __restrict__ b1,
               const float* __restrict__ W2, const float* __restrict__ b2,
               const float* __restrict__ W3, const float* __restrict__ b3,
               const float* __restrict__ W4, const float* __restrict__ b4,
               float* __restrict__ out, int B)
{
    __shared__ float actA[NH * BT];
    __shared__ float actB[NH * BT];
    __shared__ float outP[NWAVE * NC * BT];

    const int lane = threadIdx.x & 63;
    const int wid  = __builtin_amdgcn_readfirstlane((int)(threadIdx.x >> 6));
    const int g    = blockIdx.x * BT + lane;
    const int j0   = wid * JB;

    float xr[NF];
    if (g < B) {
        const float4* xp = reinterpret_cast<const float4*>(x + (size_t)g * NF);
        float4 x0 = xp[0], x1 = xp[1];
        xr[0] = x0.x; xr[1] = x0.y; xr[2] = x0.z; xr[3] = x0.w;
        xr[4] = x1.x; xr[5] = x1.y; xr[6] = x1.z; xr[7] = x1.w;
    } else {
#pragma unroll
        for (int i = 0; i < NF; ++i) xr[i] = 0.0f;
    }
    float h[NF];
#pragma unroll
    for (int j = 0; j < NF; ++j) {
        float acc = b0[j];
#pragma unroll
        for (int k = 0; k < NF; ++k) acc = fmaf(W0[j * NF + k], xr[k], acc);
        h[j] = acc;
    }
    float tq[NF], u0[NF], u1[NF];
    const float h3 = h[3];
#pragma unroll
    for (int i = 0; i < NF; ++i) {
        float s = 0.0f;
#pragma unroll
        for (int k = 0; k < NF; ++k) s = fmaf(Qi[i * NF + k], h[k], s);
        tq[i] = s;
        u0[i] = fmaf(Qi[i * NF + 4], h3, Qi[i * NF + 5]);
        u1[i] = fmaf(Qi[i * NF + 6], h3, Qi[i * NF + 7]);
    }
    const float m00 = fmaf(h3, u0[4], u0[5]);
    const float m01 = fmaf(h3, u1[4], u1[5]);
    const float m10 = fmaf(h3, u0[6], u0[7]);
    const float m11 = fmaf(h3, u1[6], u1[7]);
    const float r0  = fmaf(h3, tq[4], tq[5]) - fmaf(h3, h[4], h[5]);
    const float r1  = fmaf(h3, tq[6], tq[7]) - fmaf(h3, h[6], h[7]);
    const float idet = 1.0f / (m00 * m11 - m01 * m10);
    const float nu0 = (m11 * r0 - m01 * r1) * idet;
    const float nu1 = (m00 * r1 - m10 * r0) * idet;
    float z[NF];
#pragma unroll
    for (int i = 0; i < NF; ++i) z[i] = tq[i] - u0[i] * nu0 - u1[i] * nu1;

#pragma unroll
    for (int jj = 0; jj < JB; ++jj) {
        const int j = j0 + jj;
        float acc = b1[j];
#pragma unroll
        for (int k = 0; k < NF; ++k) acc = fmaf(W1[j * NF + k], z[k], acc);
        actA[j * BT + lane] = fmaxf(acc, 0.0f);
    }
    __syncthreads();
    layer200(actA, actB, W2, b2, j0, lane);
    __syncthreads();
    layer200(actB, actA, W3, b3, j0, lane);
    __syncthreads();
    {
        float a[JB];
#pragma unroll
        for (int kk = 0; kk < JB; ++kk) a[kk] = actA[(j0 + kk) * BT + lane];
        float acc[NC];
#pragma unroll
        for (int o = 0; o < NC; ++o) acc[o] = 0.0f;
#pragma unroll
        for (int o = 0; o < NC; ++o) {
            const float* wr = W4 + o * NH + j0;
#pragma unroll
            for (int kk = 0; kk < JB; ++kk) acc[o] = fmaf(wr[kk], a[kk], acc[o]);
        }
#pragma unroll
        for (int o = 0; o < NC; ++o) outP[(wid * NC + o) * BT + lane] = acc[o];
    }
    __syncthreads();
    {
        float s = b4[wid];
#pragma unroll
        for (int w = 0; w < NWAVE; ++w) s += outP[(w * NC + wid) * BT + lane];
        if (g < B) out[(size_t)g * NC + wid] = s;
    }
}

// ===========================================================================
extern "C" void kernel_launch(void* const* d_in, const int* in_sizes, int n_in,
                              void* d_out, int out_size, void* d_ws, size_t ws_size,
                              hipStream_t stream)
{
    const float* x  = (const float*)d_in[0];
    const float* Q  = (const float*)d_in[1];
    const float* W0 = (const float*)d_in[2];
    const float* b0 = (const float*)d_in[3];
    const float* W1 = (const float*)d_in[4];
    const float* b1 = (const float*)d_in[5];
    const float* W2 = (const float*)d_in[6];
    const float* b2 = (const float*)d_in[7];
    const float* W3 = (const float*)d_in[8];
    const float* b3 = (const float*)d_in[9];
    const float* W4 = (const float*)d_in[10];
    const float* b4 = (const float*)d_in[11];
    float* out = (float*)d_out;

    const int B = in_sizes[0] / NF;

    if (ws_size >= WS_NEED) {
        hipLaunchKernelGGL(prep_kernel, dim3(23), dim3(256), 0, stream,
                           Q, W1, b1, W2, b2, W3, b3, W4, (char*)d_ws);
        hipLaunchKernelGGL(mlp_slab1, dim3((B + M_BLK - 1) / M_BLK), dim3(64), 0, stream,
                           x, W0, b0, b4, (const char*)d_ws, out, B);
    } else {
        float* Qi = (float*)d_ws;
        hipLaunchKernelGGL(qinv_kernel, dim3(1), dim3(128), 0, stream, Q, Qi);
        hipLaunchKernelGGL(mlp_fused, dim3((B + BT - 1) / BT), dim3(BT * NWAVE), 0, stream,
                           x, Qi, W0, b0, W1, b1, W2, b2, W3, b3, W4, b4, out, B);
    }
}

// Round 6
// 49.918 us; speedup vs baseline: 1.1105x; 1.1105x over previous
//
#include <hip/hip_runtime.h>
#include <math.h>

typedef _Float16 f16;
typedef f16 half8 __attribute__((ext_vector_type(8)));
typedef float floatx4 __attribute__((ext_vector_type(4)));

#define NF 8
#define NH 200
#define NC 8
#define M_BLK 64           // rows per block (1 wave, lane = row for head)
#define SCR_W 232          // full-width scratch row stride in halfs (464B, 16B-aligned)
#define FRAG 512           // halfs per packed fragment (64 lanes x 8)

// ---- d_ws byte layout ----
#define WS_QI   0          // 64 f32
#define WS_B1P  256        // 224 f32 padded bias
#define WS_B2P  1152
#define WS_B3P  2048
#define WS_WP1  3008       // f16 frag-packed [1ks][13nt][64][8]  = 13312 B
#define WS_WP2  16320      // f16 [7][13][64][8] = 93184 B
#define WS_WP3  109504     // f16 [7][13][64][8] = 93184 B
#define WS_WP4  202688     // f16 [7][1][64][8]  = 7168 B
#define WS_NEED 212000

// ---------------------------------------------------------------------------
// Prep: block 0 inverts Q (Gauss-Jordan w/ pivoting; exact identity for Q=I).
// All blocks pack fp32 weights into B-fragment order:
//   dst[((ks*nkt+nt)*64+lane)*8+j] = W[nt*16+(lane&15)][ks*32+(lane>>4)*8+j]
// ---------------------------------------------------------------------------
__device__ __forceinline__ void pack_frag(const float* __restrict__ W, int Nv, int Kv,
                                          int nkt, int nks, f16* __restrict__ dst, int gid)
{
    if (gid < nks * nkt * 64) {
        const int ks    = gid / (nkt * 64);
        const int rem   = gid - ks * nkt * 64;
        const int nt    = rem >> 6;
        const int lane  = rem & 63;
        const int n     = nt * 16 + (lane & 15);
        const int kbase = ks * 32 + ((lane >> 4) * 8);
        f16 tmp[8];
#pragma unroll
        for (int j = 0; j < 8; ++j) {
            const int k = kbase + j;
            tmp[j] = (n < Nv && k < Kv) ? (f16)W[n * Kv + k] : (f16)0.0f;
        }
        *(half8*)&dst[(size_t)gid * 8] = *(const half8*)tmp;
    }
}

__global__ void prep_kernel(const float* __restrict__ Q,
                            const float* __restrict__ W1, const float* __restrict__ b1,
                            const float* __restrict__ W2, const float* __restrict__ b2,
                            const float* __restrict__ W3, const float* __restrict__ b3,
                            const float* __restrict__ W4,
                            char* __restrict__ ws)
{
    const int gid = blockIdx.x * 256 + threadIdx.x;
    pack_frag(W1, NH, NF, 13, 1, (f16*)(ws + WS_WP1), gid);
    pack_frag(W2, NH, NH, 13, 7, (f16*)(ws + WS_WP2), gid);
    pack_frag(W3, NH, NH, 13, 7, (f16*)(ws + WS_WP3), gid);
    pack_frag(W4, NC, NH, 1,  7, (f16*)(ws + WS_WP4), gid);
    if (gid < 224) {
        ((float*)(ws + WS_B1P))[gid] = (gid < NH) ? b1[gid] : 0.0f;
        ((float*)(ws + WS_B2P))[gid] = (gid < NH) ? b2[gid] : 0.0f;
        ((float*)(ws + WS_B3P))[gid] = (gid < NH) ? b3[gid] : 0.0f;
    }

    if (blockIdx.x == 0) {
        __shared__ float aug[8][16];
        __shared__ int piv;
        float* Qi = (float*)(ws + WS_QI);
        const int t  = threadIdx.x;
        const bool a = t < 128;
        const int r  = (t >> 4) & 7;
        const int c2 = t & 15;
        if (a) aug[r][c2] = (c2 < 8) ? Q[r * 8 + c2] : ((c2 - 8 == r) ? 1.0f : 0.0f);
        __syncthreads();
        for (int c = 0; c < 8; ++c) {
            if (t == 0) {
                int p = c; float best = fabsf(aug[c][c]);
                for (int rr = c + 1; rr < 8; ++rr) {
                    float v = fabsf(aug[rr][c]);
                    if (v > best) { best = v; p = rr; }
                }
                piv = p;
            }
            __syncthreads();
            const int p = piv;
            float myv = a ? aug[r][c2] : 0.0f;
            __syncthreads();
            if (a) {
                if (r == c)      aug[p][c2] = myv;
                else if (r == p) aug[c][c2] = myv;
            }
            __syncthreads();
            const float pv = aug[c][c];
            __syncthreads();
            if (a && r == c) aug[r][c2] = aug[r][c2] / pv;
            __syncthreads();
            const float fac  = (a && r != c) ? aug[r][c] : 0.0f;
            const float prow = aug[c][c2];
            __syncthreads();
            if (a) aug[r][c2] -= fac * prow;
            __syncthreads();
        }
        if (a && c2 >= 8) Qi[r * 8 + (c2 - 8)] = aug[r][c2];
    }
}

// ---------------------------------------------------------------------------
// Slab v2 machinery. One wave owns 64 rows (MT=4). A-frags in regs (aIn);
// B-frags from L2 with full-pass-deep double-buffered prefetch (FB ping-pong);
// per-pass epilogue writes its 32-col slice into full-width LDS scratch;
// A readback deferred to layer end (aIn overwritten in place -> no aOut).
// All register arrays statically indexed (full unroll).
// ---------------------------------------------------------------------------
struct FB { half8 f[7][2]; };   // one pass's B-fragments (up to 7 ks x 2 nt)

__device__ __forceinline__ half8 ldf(const f16* __restrict__ p, int lane)
{
    return *(const half8*)&p[lane * 8];
}

template<int NKS, int NT, int NKT>
__device__ __forceinline__ void loadp(const f16* __restrict__ Wp, int pp, FB& w, int lane)
{
#pragma unroll
    for (int ks = 0; ks < NKS; ++ks)
#pragma unroll
        for (int t = 0; t < NT; ++t)
            w.f[ks][t] = ldf(Wp + (size_t)(ks * NKT + 2 * pp + t) * FRAG, lane);
}

template<int NKS, int NT>
__device__ __forceinline__ void mma_pass(const half8 (&aIn)[4][7], const FB& w,
                                         floatx4 (&acc)[4][2])
{
#pragma unroll
    for (int ks = 0; ks < NKS; ++ks)
#pragma unroll
        for (int mt = 0; mt < 4; ++mt)
#pragma unroll
            for (int t = 0; t < NT; ++t)
                acc[mt][t] = __builtin_amdgcn_mfma_f32_16x16x32_f16(
                    aIn[mt][ks], w.f[ks][t], acc[mt][t], 0, 0, 0);
}

template<int NT>
__device__ __forceinline__ void epil(const floatx4 (&acc)[4][2], float b0, float b1,
                                     f16* __restrict__ scr, int pp, int col16, int g4)
{
#pragma unroll
    for (int mt = 0; mt < 4; ++mt)
#pragma unroll
        for (int r = 0; r < 4; ++r) {
            const int row = mt * 16 + g4 * 4 + r;
            scr[row * SCR_W + 2 * pp * 16 + col16] = (f16)fmaxf(acc[mt][0][r] + b0, 0.0f);
            if (NT == 2)
                scr[row * SCR_W + (2 * pp + 1) * 16 + col16] = (f16)fmaxf(acc[mt][1][r] + b1, 0.0f);
        }
}

// One 13-n-tile layer: passes P0..P6 (P0..P5 NT=2, P6 NT=1). Entry: w0 holds
// this layer's P0 frags. Exit: w1 holds NEXT layer's P0 frags; aIn refreshed.
template<int LK, int NXK, int NXNT, int NXNKT>
__device__ __forceinline__ void layer13(const f16* __restrict__ Wp,
                                        const f16* __restrict__ WpN,
                                        const float* __restrict__ biasP,
                                        half8 (&aIn)[4][7], FB& w0, FB& w1,
                                        f16* __restrict__ scr,
                                        int lane, int col16, int g4)
{
    { // P0 (cur = w0)
        loadp<LK, 2, 13>(Wp, 1, w1, lane);
        const float b0 = biasP[0 * 16 + col16], b1 = biasP[1 * 16 + col16];
        floatx4 acc[4][2] = {};
        mma_pass<LK, 2>(aIn, w0, acc);
        epil<2>(acc, b0, b1, scr, 0, col16, g4);
    }
    { // P1 (cur = w1)
        loadp<LK, 2, 13>(Wp, 2, w0, lane);
        const float b0 = biasP[2 * 16 + col16], b1 = biasP[3 * 16 + col16];
        floatx4 acc[4][2] = {};
        mma_pass<LK, 2>(aIn, w1, acc);
        epil<2>(acc, b0, b1, scr, 1, col16, g4);
    }
    { // P2 (cur = w0)
        loadp<LK, 2, 13>(Wp, 3, w1, lane);
        const float b0 = biasP[4 * 16 + col16], b1 = biasP[5 * 16 + col16];
        floatx4 acc[4][2] = {};
        mma_pass<LK, 2>(aIn, w0, acc);
        epil<2>(acc, b0, b1, scr, 2, col16, g4);
    }
    { // P3 (cur = w1)
        loadp<LK, 2, 13>(Wp, 4, w0, lane);
        const float b0 = biasP[6 * 16 + col16], b1 = biasP[7 * 16 + col16];
        floatx4 acc[4][2] = {};
        mma_pass<LK, 2>(aIn, w1, acc);
        epil<2>(acc, b0, b1, scr, 3, col16, g4);
    }
    { // P4 (cur = w0)
        loadp<LK, 2, 13>(Wp, 5, w1, lane);
        const float b0 = biasP[8 * 16 + col16], b1 = biasP[9 * 16 + col16];
        floatx4 acc[4][2] = {};
        mma_pass<LK, 2>(aIn, w0, acc);
        epil<2>(acc, b0, b1, scr, 4, col16, g4);
    }
    { // P5 (cur = w1); load P6 (single tile)
        loadp<LK, 1, 13>(Wp, 6, w0, lane);
        const float b0 = biasP[10 * 16 + col16], b1 = biasP[11 * 16 + col16];
        floatx4 acc[4][2] = {};
        mma_pass<LK, 2>(aIn, w1, acc);
        epil<2>(acc, b0, b1, scr, 5, col16, g4);
    }
    { // P6 (cur = w0, NT=1); load NEXT layer's P0 into w1
        loadp<NXK, NXNT, NXNKT>(WpN, 0, w1, lane);
        const float b0 = biasP[12 * 16 + col16];
        floatx4 acc[4][2] = {};
        mma_pass<LK, 1>(aIn, w0, acc);
        epil<1>(acc, b0, 0.0f, scr, 6, col16, g4);
    }
    // deferred readback: refresh ALL A-frags for the next layer (aIn now dead)
#pragma unroll
    for (int mt = 0; mt < 4; ++mt)
#pragma unroll
        for (int ks = 0; ks < 7; ++ks)
            aIn[mt][ks] = *(const half8*)&scr[(mt * 16 + col16) * SCR_W + ks * 32 + g4 * 8];
}

// ---------------------------------------------------------------------------
// Slab v2 kernel: 1 wave / block, 64 rows; head -> L1 -> L2 -> L3 -> L4.
// No barriers anywhere. ~280 VGPR by design -> 1 wave/SIMD, 4 blocks/CU.
// ---------------------------------------------------------------------------
__global__ __launch_bounds__(64, 1)
void mlp_slab2(const float* __restrict__ x,
               const float* __restrict__ W0, const float* __restrict__ b0,
               const float* __restrict__ b4,
               const char* __restrict__ ws,
               float* __restrict__ out, int B)
{
    __shared__ f16 scr[M_BLK * SCR_W];             // 29696 B (one wave per block)
    const int lane  = threadIdx.x & 63;
    const int col16 = lane & 15;
    const int g4    = lane >> 4;

    const float* Qi  = (const float*)(ws + WS_QI);
    const float* b1p = (const float*)(ws + WS_B1P);
    const float* b2p = (const float*)(ws + WS_B2P);
    const float* b3p = (const float*)(ws + WS_B3P);
    const f16*  Wp1  = (const f16*)(ws + WS_WP1);
    const f16*  Wp2  = (const f16*)(ws + WS_WP2);
    const f16*  Wp3  = (const f16*)(ws + WS_WP3);
    const f16*  Wp4  = (const f16*)(ws + WS_WP4);

    FB wA, wB;
    // start the prefetch chain: L1 P0 frags in flight over the head compute
    loadp<1, 2, 13>(Wp1, 0, wA, lane);

    // zero cols [208,232) once; they stay zero for every layer's k-pad
    {
        half8 zz = {};
        *(half8*)&scr[lane * SCR_W + 208] = zz;
        *(half8*)&scr[lane * SCR_W + 216] = zz;
        *(half8*)&scr[lane * SCR_W + 224] = zz;
    }

    // ---- head: fc0 + reduced-KKT QP (fp32); lane l owns row blk*64 + l ----
    const long g0 = (long)blockIdx.x * M_BLK + lane;
    float xr[NF];
    if (g0 < B) {
        const float4* xp = (const float4*)(x + g0 * NF);
        const float4 A = xp[0], Bv = xp[1];
        xr[0] = A.x; xr[1] = A.y; xr[2] = A.z; xr[3] = A.w;
        xr[4] = Bv.x; xr[5] = Bv.y; xr[6] = Bv.z; xr[7] = Bv.w;
    } else {
#pragma unroll
        for (int i = 0; i < NF; ++i) xr[i] = 0.0f;
    }
    float h[NF];
#pragma unroll
    for (int j = 0; j < NF; ++j) {
        float acc = b0[j];
#pragma unroll
        for (int k = 0; k < NF; ++k) acc = fmaf(W0[j * NF + k], xr[k], acc);
        h[j] = acc;
    }
    // z = Qi h - Qi A' nu, nu = (A Qi A')^-1 (A Qi h - A h); exact z = h for Q = I
    float tq[NF], u0[NF], u1[NF];
    const float h3 = h[3];
#pragma unroll
    for (int i = 0; i < NF; ++i) {
        float s = 0.0f;
#pragma unroll
        for (int k = 0; k < NF; ++k) s = fmaf(Qi[i * NF + k], h[k], s);
        tq[i] = s;
        u0[i] = fmaf(Qi[i * NF + 4], h3, Qi[i * NF + 5]);
        u1[i] = fmaf(Qi[i * NF + 6], h3, Qi[i * NF + 7]);
    }
    const float m00 = fmaf(h3, u0[4], u0[5]);
    const float m01 = fmaf(h3, u1[4], u1[5]);
    const float m10 = fmaf(h3, u0[6], u0[7]);
    const float m11 = fmaf(h3, u1[6], u1[7]);
    const float r0  = fmaf(h3, tq[4], tq[5]) - fmaf(h3, h[4], h[5]);
    const float r1  = fmaf(h3, tq[6], tq[7]) - fmaf(h3, h[6], h[7]);
    const float idet = 1.0f / (m00 * m11 - m01 * m10);
    const float nu0 = (m11 * r0 - m01 * r1) * idet;
    const float nu1 = (m00 * r1 - m10 * r0) * idet;

    {
        half8 zh, zz = {};
#pragma unroll
        for (int k = 0; k < 8; ++k) zh[k] = (f16)(tq[k] - u0[k] * nu0 - u1[k] * nu1);
        *(half8*)&scr[lane * SCR_W + 0]  = zh;   // cols 0..7 = z
        *(half8*)&scr[lane * SCR_W + 8]  = zz;   // cols 8..31 = 0 (L1 k-pad)
        *(half8*)&scr[lane * SCR_W + 16] = zz;
        *(half8*)&scr[lane * SCR_W + 24] = zz;
    }

    half8 aIn[4][7];
#pragma unroll
    for (int mt = 0; mt < 4; ++mt)
        aIn[mt][0] = *(const half8*)&scr[(mt * 16 + col16) * SCR_W + g4 * 8];

    layer13<1, 7, 2, 13>(Wp1, Wp2, b1p, aIn, wA, wB, scr, lane, col16, g4);  // L1
    layer13<7, 7, 2, 13>(Wp2, Wp3, b2p, aIn, wB, wA, scr, lane, col16, g4);  // L2
    layer13<7, 7, 1, 1 >(Wp3, Wp4, b3p, aIn, wA, wB, scr, lane, col16, g4);  // L3

    // ---- L4: 200 -> 8 (wB holds Wp4 frags from L3's chain) ----
    {
        floatx4 a4[4] = {};
#pragma unroll
        for (int ks = 0; ks < 7; ++ks)
#pragma unroll
            for (int mt = 0; mt < 4; ++mt)
                a4[mt] = __builtin_amdgcn_mfma_f32_16x16x32_f16(
                    aIn[mt][ks], wB.f[ks][0], a4[mt], 0, 0, 0);
        if (col16 < NC) {
            const float bias4 = b4[col16];
            const long rowbase = (long)blockIdx.x * M_BLK;
#pragma unroll
            for (int mt = 0; mt < 4; ++mt)
#pragma unroll
                for (int r = 0; r < 4; ++r) {
                    const long g = rowbase + mt * 16 + g4 * 4 + r;
                    if (g < B) out[g * NC + col16] = a4[mt][r] + bias4;
                }
        }
    }
}

// ===========================================================================
// Fallback fp32 path if ws_size is too small for prep data.
// ===========================================================================
#define BT 64
#define NWAVE 8
#define JB 25
#define CH 8

__device__ __forceinline__ void layer200(const float* __restrict__ in_,
                                         float* __restrict__ out_,
                                         const float* __restrict__ W,
                                         const float* __restrict__ bias,
                                         int j0, int lane)
{
    float acc[JB];
#pragma unroll
    for (int jj = 0; jj < JB; ++jj) acc[jj] = bias[j0 + jj];
#pragma unroll 1
    for (int k0 = 0; k0 < NH; k0 += CH) {
        float a[CH];
#pragma unroll
        for (int u = 0; u < CH; ++u) a[u] = in_[(k0 + u) * BT + lane];
#pragma unroll
        for (int jj = 0; jj < JB; ++jj) {
            const float* wr = W + (j0 + jj) * NH + k0;
#pragma unroll
            for (int u = 0; u < CH; ++u) acc[jj] = fmaf(wr[u], a[u], acc[jj]);
        }
    }
#pragma unroll
    for (int jj = 0; jj < JB; ++jj)
        out_[(j0 + jj) * BT + lane] = fmaxf(acc[jj], 0.0f);
}

__global__ void qinv_kernel(const float* __restrict__ Q, float* __restrict__ Qi)
{
    __shared__ float aug[8][16];
    __shared__ int piv;
    const int t  = threadIdx.x;
    const int r  = t >> 4;
    const int c2 = t & 15;
    aug[r][c2] = (c2 < 8) ? Q[r * 8 + c2] : ((c2 - 8 == r) ? 1.0f : 0.0f);
    __syncthreads();
    for (int c = 0; c < 8; ++c) {
        if (t == 0) {
            int p = c; float best = fabsf(aug[c][c]);
            for (int rr = c + 1; rr < 8; ++rr) {
                float v = fabsf(aug[rr][c]);
                if (v > best) { best = v; p = rr; }
            }
            piv = p;
        }
        __syncthreads();
        const int p = piv;
        float myv = aug[r][c2];
        __syncthreads();
        if (r == c)      aug[p][c2] = myv;
        else if (r == p) aug[c][c2] = myv;
        __syncthreads();
        const float pv = aug[c][c];
        __syncthreads();
        if (r == c) aug[r][c2] = aug[r][c2] / pv;
        __syncthreads();
        const float fac  = (r == c) ? 0.0f : aug[r][c];
        const float prow = aug[c][c2];
        __syncthreads();
        aug[r][c2] -= fac * prow;
        __syncthreads();
    }
    if (c2 >= 8) Qi[r * 8 + (c2 - 8)] = aug[r][c2];
}

__global__ __launch_bounds__(BT * NWAVE, 2)
void mlp_fused(const float* __restrict__ x, const float* __restrict__ Qi,
               const float* __restrict__ W0, const float* __restrict__ b0,
               const float* __restrict__ W1, const float* __restrict__ b1,
               const float* __restrict__ W2, const float* __restrict__ b2,
               const float* __restrict__ W3, const float* __restrict__ b3,
               const float* __restrict__ W4, const float* __restrict__ b4,
               float* __restrict__ out, int B)
{
    __shared__ float actA[NH * BT];
    __shared__ float actB[NH * BT];
    __shared__ float outP[NWAVE * NC * BT];

    const int lane = threadIdx.x & 63;
    const int wid  = __builtin_amdgcn_readfirstlane((int)(threadIdx.x >> 6));
    const int g    = blockIdx.x * BT + lane;
    const int j0   = wid * JB;

    float xr[NF];
    if (g < B) {
        const float4* xp = reinterpret_cast<const float4*>(x + (size_t)g * NF);
        float4 x0 = xp[0], x1 = xp[1];
        xr[0] = x0.x; xr[1] = x0.y; xr[2] = x0.z; xr[3] = x0.w;
        xr[4] = x1.x; xr[5] = x1.y; xr[6] = x1.z; xr[7] = x1.w;
    } else {
#pragma unroll
        for (int i = 0; i < NF; ++i) xr[i] = 0.0f;
    }
    float h[NF];
#pragma unroll
    for (int j = 0; j < NF; ++j) {
        float acc = b0[j];
#pragma unroll
        for (int k = 0; k < NF; ++k) acc = fmaf(W0[j * NF + k], xr[k], acc);
        h[j] = acc;
    }
    float tq[NF], u0[NF], u1[NF];
    const float h3 = h[3];
#pragma unroll
    for (int i = 0; i < NF; ++i) {
        float s = 0.0f;
#pragma unroll
        for (int k = 0; k < NF; ++k) s = fmaf(Qi[i * NF + k], h[k], s);
        tq[i] = s;
        u0[i] = fmaf(Qi[i * NF + 4], h3, Qi[i * NF + 5]);
        u1[i] = fmaf(Qi[i * NF + 6], h3, Qi[i * NF + 7]);
    }
    const float m00 = fmaf(h3, u0[4], u0[5]);
    const float m01 = fmaf(h3, u1[4], u1[5]);
    const float m10 = fmaf(h3, u0[6], u0[7]);
    const float m11 = fmaf(h3, u1[6], u1[7]);
    const float r0  = fmaf(h3, tq[4], tq[5]) - fmaf(h3, h[4], h[5]);
    const float r1  = fmaf(h3, tq[6], tq[7]) - fmaf(h3, h[6], h[7]);
    const float idet = 1.0f / (m00 * m11 - m01 * m10);
    const float nu0 = (m11 * r0 - m01 * r1) * idet;
    const float nu1 = (m00 * r1 - m10 * r0) * idet;
    float z[NF];
#pragma unroll
    for (int i = 0; i < NF; ++i) z[i] = tq[i] - u0[i] * nu0 - u1[i] * nu1;

#pragma unroll
    for (int jj = 0; jj < JB; ++jj) {
        const int j = j0 + jj;
        float acc = b1[j];
#pragma unroll
        for (int k = 0; k < NF; ++k) acc = fmaf(W1[j * NF + k], z[k], acc);
        actA[j * BT + lane] = fmaxf(acc, 0.0f);
    }
    __syncthreads();
    layer200(actA, actB, W2, b2, j0, lane);
    __syncthreads();
    layer200(actB, actA, W3, b3, j0, lane);
    __syncthreads();
    {
        float a[JB];
#pragma unroll
        for (int kk = 0; kk < JB; ++kk) a[kk] = actA[(j0 + kk) * BT + lane];
        float acc[NC];
#pragma unroll
        for (int o = 0; o < NC; ++o) acc[o] = 0.0f;
#pragma unroll
        for (int o = 0; o < NC; ++o) {
            const float* wr = W4 + o * NH + j0;
#pragma unroll
            for (int kk = 0; kk < JB; ++kk) acc[o] = fmaf(wr[kk], a[kk], acc[o]);
        }
#pragma unroll
        for (int o = 0; o < NC; ++o) outP[(wid * NC + o) * BT + lane] = acc[o];
    }
    __syncthreads();
    {
        float s = b4[wid];
#pragma unroll
        for (int w = 0; w < NWAVE; ++w) s += outP[(w * NC + wid) * BT + lane];
        if (g < B) out[(size_t)g * NC + wid] = s;
    }
}

// ===========================================================================
extern "C" void kernel_launch(void* const* d_in, const int* in_sizes, int n_in,
                              void* d_out, int out_size, void* d_ws, size_t ws_size,
                              hipStream_t stream)
{
    const float* x  = (const float*)d_in[0];
    const float* Q  = (const float*)d_in[1];
    const float* W0 = (const float*)d_in[2];
    const float* b0 = (const float*)d_in[3];
    const float* W1 = (const float*)d_in[4];
    const float* b1 = (const float*)d_in[5];
    const float* W2 = (const float*)d_in[6];
    const float* b2 = (const float*)d_in[7];
    const float* W3 = (const float*)d_in[8];
    const float* b3 = (const float*)d_in[9];
    const float* W4 = (const float*)d_in[10];
    const float* b4 = (const float*)d_in[11];
    float* out = (float*)d_out;

    const int B = in_sizes[0] / NF;

    if (ws_size >= WS_NEED) {
        hipLaunchKernelGGL(prep_kernel, dim3(23), dim3(256), 0, stream,
                           Q, W1, b1, W2, b2, W3, b3, W4, (char*)d_ws);
        hipLaunchKernelGGL(mlp_slab2, dim3((B + M_BLK - 1) / M_BLK), dim3(64), 0, stream,
                           x, W0, b0, b4, (const char*)d_ws, out, B);
    } else {
        float* Qi = (float*)d_ws;
        hipLaunchKernelGGL(qinv_kernel, dim3(1), dim3(128), 0, stream, Q, Qi);
        hipLaunchKernelGGL(mlp_fused, dim3((B + BT - 1) / BT), dim3(BT * NWAVE), 0, stream,
                           x, Qi, W0, b0, W1, b1, W2, b2, W3, b3, W4, b4, out, B);
    }
}

// Round 7
// 48.770 us; speedup vs baseline: 1.1366x; 1.0235x over previous
//
#include <hip/hip_runtime.h>
#include <math.h>

typedef _Float16 f16;
typedef f16 half8 __attribute__((ext_vector_type(8)));
typedef float floatx4 __attribute__((ext_vector_type(4)));

#define NF 8
#define NH 200
#define NC 8
#define M_BLK 64           // rows per block (2 waves share them, split by N)
#define SCR_W 232          // scratch row stride in halfs (464B)
#define FRAG 512           // halfs per packed fragment (64 lanes x 8)

// ---- d_ws byte layout ----
#define WS_QI   0          // 64 f32
#define WS_B1P  256        // 224 f32 padded bias
#define WS_B2P  1152
#define WS_B3P  2048
#define WS_WP1  3008       // f16 frag-packed [1ks][13nt][64][8]  = 13312 B
#define WS_WP2  16320      // f16 [7][13][64][8] = 93184 B
#define WS_WP3  109504     // f16 [7][13][64][8] = 93184 B
#define WS_WP4  202688     // f16 [7][1][64][8]  = 7168 B
#define WS_NEED 212000

// ---------------------------------------------------------------------------
// Prep: block 0 inverts Q (Gauss-Jordan w/ pivoting; exact identity for Q=I).
// All blocks pack fp32 weights into B-fragment order:
//   dst[((ks*nkt+nt)*64+lane)*8+j] = W[nt*16+(lane&15)][ks*32+(lane>>4)*8+j]
// ---------------------------------------------------------------------------
__device__ __forceinline__ void pack_frag(const float* __restrict__ W, int Nv, int Kv,
                                          int nkt, int nks, f16* __restrict__ dst, int gid)
{
    if (gid < nks * nkt * 64) {
        const int ks    = gid / (nkt * 64);
        const int rem   = gid - ks * nkt * 64;
        const int nt    = rem >> 6;
        const int lane  = rem & 63;
        const int n     = nt * 16 + (lane & 15);
        const int kbase = ks * 32 + ((lane >> 4) * 8);
        f16 tmp[8];
#pragma unroll
        for (int j = 0; j < 8; ++j) {
            const int k = kbase + j;
            tmp[j] = (n < Nv && k < Kv) ? (f16)W[n * Kv + k] : (f16)0.0f;
        }
        *(half8*)&dst[(size_t)gid * 8] = *(const half8*)tmp;
    }
}

__global__ void prep_kernel(const float* __restrict__ Q,
                            const float* __restrict__ W1, const float* __restrict__ b1,
                            const float* __restrict__ W2, const float* __restrict__ b2,
                            const float* __restrict__ W3, const float* __restrict__ b3,
                            const float* __restrict__ W4,
                            char* __restrict__ ws)
{
    const int gid = blockIdx.x * 256 + threadIdx.x;
    pack_frag(W1, NH, NF, 13, 1, (f16*)(ws + WS_WP1), gid);
    pack_frag(W2, NH, NH, 13, 7, (f16*)(ws + WS_WP2), gid);
    pack_frag(W3, NH, NH, 13, 7, (f16*)(ws + WS_WP3), gid);
    pack_frag(W4, NC, NH, 1,  7, (f16*)(ws + WS_WP4), gid);
    if (gid < 224) {
        ((float*)(ws + WS_B1P))[gid] = (gid < NH) ? b1[gid] : 0.0f;
        ((float*)(ws + WS_B2P))[gid] = (gid < NH) ? b2[gid] : 0.0f;
        ((float*)(ws + WS_B3P))[gid] = (gid < NH) ? b3[gid] : 0.0f;
    }

    if (blockIdx.x == 0) {
        __shared__ float aug[8][16];
        __shared__ int piv;
        float* Qi = (float*)(ws + WS_QI);
        const int t  = threadIdx.x;
        const bool a = t < 128;
        const int r  = (t >> 4) & 7;
        const int c2 = t & 15;
        if (a) aug[r][c2] = (c2 < 8) ? Q[r * 8 + c2] : ((c2 - 8 == r) ? 1.0f : 0.0f);
        __syncthreads();
        for (int c = 0; c < 8; ++c) {
            if (t == 0) {
                int p = c; float best = fabsf(aug[c][c]);
                for (int rr = c + 1; rr < 8; ++rr) {
                    float v = fabsf(aug[rr][c]);
                    if (v > best) { best = v; p = rr; }
                }
                piv = p;
            }
            __syncthreads();
            const int p = piv;
            float myv = a ? aug[r][c2] : 0.0f;
            __syncthreads();
            if (a) {
                if (r == c)      aug[p][c2] = myv;
                else if (r == p) aug[c][c2] = myv;
            }
            __syncthreads();
            const float pv = aug[c][c];
            __syncthreads();
            if (a && r == c) aug[r][c2] = aug[r][c2] / pv;
            __syncthreads();
            const float fac  = (a && r != c) ? aug[r][c] : 0.0f;
            const float prow = aug[c][c2];
            __syncthreads();
            if (a) aug[r][c2] -= fac * prow;
            __syncthreads();
        }
        if (a && c2 >= 8) Qi[r * 8 + (c2 - 8)] = aug[r][c2];
    }
}

// ---------------------------------------------------------------------------
// N-split slab machinery. Two waves share a 64-row block: wave0 computes
// n-tiles 0..6, wave1 tiles 7..12 (+L4 uses both). A-frags in regs; B-frags
// from L2, single fb[7] buffer, reloaded per-ks right after last consumer
// (interleaved in the MFMA loop -> ~600cy latency cover). Per-pass epilogue
// writes its 16-col slice into shared LDS scratch; readback after barrier.
// ---------------------------------------------------------------------------
__device__ __forceinline__ half8 ldf(const f16* __restrict__ p, int lane)
{
    return *(const half8*)&p[lane * 8];
}

__device__ __forceinline__ void epilT(const floatx4 (&acc)[4], float bv,
                                      f16* __restrict__ scr, int tile,
                                      int col16, int g4)
{
#pragma unroll
    for (int mt = 0; mt < 4; ++mt)
#pragma unroll
        for (int r = 0; r < 4; ++r)
            scr[(mt * 16 + g4 * 4 + r) * SCR_W + tile * 16 + col16] =
                (f16)fmaxf(acc[mt][r] + bv, 0.0f);
}

// One layer for one wave: NTILES passes of 1 n-tile, LK ksteps each.
// On the last pass the prefetch chain loads the NEXT layer's first tile
// (LKN frags, fragment stride NKTN).
template<int LK, int NTILES, int LKN, int NKTN>
__device__ __forceinline__ void layer_run(
    const f16* __restrict__ Wp, int tbase,
    const f16* __restrict__ WpN, int tbaseN,
    const float* __restrict__ biasP,
    const half8 (&aIn)[4][7], half8 (&fb)[7],
    f16* __restrict__ scr, int lane, int col16, int g4)
{
#pragma unroll
    for (int p = 0; p < NTILES; ++p) {
        const float bv = biasP[(tbase + p) * 16 + col16];
        const bool last = (p + 1 == NTILES);
        const f16* nb = last ? (WpN + (size_t)tbaseN * FRAG)
                             : (Wp + (size_t)(tbase + p + 1) * FRAG);
        const size_t nstride = (size_t)(last ? NKTN : 13) * FRAG;
        floatx4 acc[4] = {};
#pragma unroll
        for (int ks = 0; ks < LK; ++ks) {
#pragma unroll
            for (int mt = 0; mt < 4; ++mt)
                acc[mt] = __builtin_amdgcn_mfma_f32_16x16x32_f16(
                    aIn[mt][ks], fb[ks], acc[mt], 0, 0, 0);
            if (LK == 7)                       // interleaved next-tile load
                fb[ks] = ldf(nb + ks * nstride, lane);
        }
        if (LK != 7) {                         // L1 path (1 kstep)
            if (!last) fb[0] = ldf(nb, lane);
            else {
#pragma unroll
                for (int ks = 0; ks < LKN; ++ks)
                    fb[ks] = ldf(nb + ks * nstride, lane);
            }
        }
        epilT(acc, bv, scr, tbase + p, col16, g4);
    }
}

__device__ __forceinline__ void readA(half8 (&aIn)[4][7], const f16* __restrict__ scr,
                                      int col16, int g4)
{
#pragma unroll
    for (int mt = 0; mt < 4; ++mt)
#pragma unroll
        for (int ks = 0; ks < 7; ++ks)
            aIn[mt][ks] = *(const half8*)&scr[(mt * 16 + col16) * SCR_W + ks * 32 + g4 * 8];
}

// ---------------------------------------------------------------------------
// Kernel: 2 waves / 64 rows; head -> L1 -> L2 -> L3 -> L4.
// ---------------------------------------------------------------------------
__global__ __launch_bounds__(128, 2)
void mlp_ns(const float* __restrict__ x,
            const float* __restrict__ W0, const float* __restrict__ b0,
            const float* __restrict__ b4,
            const char* __restrict__ ws,
            float* __restrict__ out, int B)
{
    __shared__ f16 scr[M_BLK * SCR_W];             // 29696 B, shared by 2 waves
    const int tid   = threadIdx.x;
    const int lane  = tid & 63;
    const int wid   = __builtin_amdgcn_readfirstlane(tid >> 6);
    const int col16 = lane & 15;
    const int g4    = lane >> 4;
    const int tb    = wid ? 7 : 0;                 // this wave's first n-tile

    const float* Qi  = (const float*)(ws + WS_QI);
    const float* b1p = (const float*)(ws + WS_B1P);
    const float* b2p = (const float*)(ws + WS_B2P);
    const float* b3p = (const float*)(ws + WS_B3P);
    const f16*  Wp1  = (const f16*)(ws + WS_WP1);
    const f16*  Wp2  = (const f16*)(ws + WS_WP2);
    const f16*  Wp3  = (const f16*)(ws + WS_WP3);
    const f16*  Wp4  = (const f16*)(ws + WS_WP4);

    // start the prefetch chain: this wave's L1 first frag in flight over head
    half8 fb[7];
    fb[0] = ldf(Wp1 + (size_t)tb * FRAG, lane);

    // ---- head (threads 0..63): fc0 + reduced-KKT QP (fp32), row = tid ----
    if (tid < M_BLK) {
        // zero pad cols [208,232): read by ks=6 readback, never written again
        half8 zz = {};
        *(half8*)&scr[tid * SCR_W + 208] = zz;
        *(half8*)&scr[tid * SCR_W + 216] = zz;
        *(half8*)&scr[tid * SCR_W + 224] = zz;

        const long g0 = (long)blockIdx.x * M_BLK + tid;
        float xr[NF];
        if (g0 < B) {
            const float4* xp = (const float4*)(x + g0 * NF);
            const float4 A = xp[0], Bv = xp[1];
            xr[0] = A.x; xr[1] = A.y; xr[2] = A.z; xr[3] = A.w;
            xr[4] = Bv.x; xr[5] = Bv.y; xr[6] = Bv.z; xr[7] = Bv.w;
        } else {
#pragma unroll
            for (int i = 0; i < NF; ++i) xr[i] = 0.0f;
        }
        float h[NF];
#pragma unroll
        for (int j = 0; j < NF; ++j) {
            float acc = b0[j];
#pragma unroll
            for (int k = 0; k < NF; ++k) acc = fmaf(W0[j * NF + k], xr[k], acc);
            h[j] = acc;
        }
        // z = Qi h - Qi A' nu, nu = (A Qi A')^-1 (A Qi h - A h); z = h for Q = I
        float tq[NF], u0[NF], u1[NF];
        const float h3 = h[3];
#pragma unroll
        for (int i = 0; i < NF; ++i) {
            float s = 0.0f;
#pragma unroll
            for (int k = 0; k < NF; ++k) s = fmaf(Qi[i * NF + k], h[k], s);
            tq[i] = s;
            u0[i] = fmaf(Qi[i * NF + 4], h3, Qi[i * NF + 5]);
            u1[i] = fmaf(Qi[i * NF + 6], h3, Qi[i * NF + 7]);
        }
        const float m00 = fmaf(h3, u0[4], u0[5]);
        const float m01 = fmaf(h3, u1[4], u1[5]);
        const float m10 = fmaf(h3, u0[6], u0[7]);
        const float m11 = fmaf(h3, u1[6], u1[7]);
        const float r0  = fmaf(h3, tq[4], tq[5]) - fmaf(h3, h[4], h[5]);
        const float r1  = fmaf(h3, tq[6], tq[7]) - fmaf(h3, h[6], h[7]);
        const float idet = 1.0f / (m00 * m11 - m01 * m10);
        const float nu0 = (m11 * r0 - m01 * r1) * idet;
        const float nu1 = (m00 * r1 - m10 * r0) * idet;

        half8 zh, zz2 = {};
#pragma unroll
        for (int k = 0; k < 8; ++k) zh[k] = (f16)(tq[k] - u0[k] * nu0 - u1[k] * nu1);
        *(half8*)&scr[tid * SCR_W + 0]  = zh;   // cols 0..7 = z
        *(half8*)&scr[tid * SCR_W + 8]  = zz2;  // cols 8..31 = 0 (L1 k-pad)
        *(half8*)&scr[tid * SCR_W + 16] = zz2;
        *(half8*)&scr[tid * SCR_W + 24] = zz2;
    }
    __syncthreads();                               // head acts visible

    half8 aIn[4][7];
#pragma unroll
    for (int mt = 0; mt < 4; ++mt)                 // L1 A-frags (ks=0 only)
        aIn[mt][0] = *(const half8*)&scr[(mt * 16 + col16) * SCR_W + g4 * 8];
    __syncthreads();                               // readbacks before L1 writes

    if (wid == 0) layer_run<1, 7, 7, 13>(Wp1, 0, Wp2, 0, b1p, aIn, fb, scr, lane, col16, g4);
    else          layer_run<1, 6, 7, 13>(Wp1, 7, Wp2, 7, b1p, aIn, fb, scr, lane, col16, g4);
    __syncthreads();                               // L1 output complete
    readA(aIn, scr, col16, g4);
    __syncthreads();                               // readbacks before L2 writes

    if (wid == 0) layer_run<7, 7, 7, 13>(Wp2, 0, Wp3, 0, b2p, aIn, fb, scr, lane, col16, g4);
    else          layer_run<7, 6, 7, 13>(Wp2, 7, Wp3, 7, b2p, aIn, fb, scr, lane, col16, g4);
    __syncthreads();
    readA(aIn, scr, col16, g4);
    __syncthreads();

    if (wid == 0) layer_run<7, 7, 7, 1>(Wp3, 0, Wp4, 0, b3p, aIn, fb, scr, lane, col16, g4);
    else          layer_run<7, 6, 7, 1>(Wp3, 7, Wp4, 0, b3p, aIn, fb, scr, lane, col16, g4);
    __syncthreads();                               // L3 output complete

    // ---- L4: 200 -> 8. fb holds W4's 7 frags (both waves). Split rows:
    //      wave w handles m-tiles {2w, 2w+1} (rows 32w .. 32w+31).
    {
        half8 aw[2][7];
#pragma unroll
        for (int m2 = 0; m2 < 2; ++m2)
#pragma unroll
            for (int ks = 0; ks < 7; ++ks)
                aw[m2][ks] = *(const half8*)&scr[((wid * 2 + m2) * 16 + col16) * SCR_W
                                                 + ks * 32 + g4 * 8];
        floatx4 a4[2] = {};
#pragma unroll
        for (int ks = 0; ks < 7; ++ks)
#pragma unroll
            for (int m2 = 0; m2 < 2; ++m2)
                a4[m2] = __builtin_amdgcn_mfma_f32_16x16x32_f16(
                    aw[m2][ks], fb[ks], a4[m2], 0, 0, 0);
        if (col16 < NC) {
            const float bias4 = b4[col16];
            const long rowbase = (long)blockIdx.x * M_BLK + wid * 32;
#pragma unroll
            for (int m2 = 0; m2 < 2; ++m2)
#pragma unroll
                for (int r = 0; r < 4; ++r) {
                    const long g = rowbase + m2 * 16 + g4 * 4 + r;
                    if (g < B) out[g * NC + col16] = a4[m2][r] + bias4;
                }
        }
    }
}

// ===========================================================================
// Fallback fp32 path if ws_size is too small for prep data.
// ===========================================================================
#define BT 64
#define NWAVE 8
#define JB 25
#define CH 8

__device__ __forceinline__ void layer200(const float* __restrict__ in_,
                                         float* __restrict__ out_,
                                         const float* __restrict__ W,
                                         const float* __restrict__ bias,
                                         int j0, int lane)
{
    float acc[JB];
#pragma unroll
    for (int jj = 0; jj < JB; ++jj) acc[jj] = bias[j0 + jj];
#pragma unroll 1
    for (int k0 = 0; k0 < NH; k0 += CH) {
        float a[CH];
#pragma unroll
        for (int u = 0; u < CH; ++u) a[u] = in_[(k0 + u) * BT + lane];
#pragma unroll
        for (int jj = 0; jj < JB; ++jj) {
            const float* wr = W + (j0 + jj) * NH + k0;
#pragma unroll
            for (int u = 0; u < CH; ++u) acc[jj] = fmaf(wr[u], a[u], acc[jj]);
        }
    }
#pragma unroll
    for (int jj = 0; jj < JB; ++jj)
        out_[(j0 + jj) * BT + lane] = fmaxf(acc[jj], 0.0f);
}

__global__ void qinv_kernel(const float* __restrict__ Q, float* __restrict__ Qi)
{
    __shared__ float aug[8][16];
    __shared__ int piv;
    const int t  = threadIdx.x;
    const int r  = t >> 4;
    const int c2 = t & 15;
    aug[r][c2] = (c2 < 8) ? Q[r * 8 + c2] : ((c2 - 8 == r) ? 1.0f : 0.0f);
    __syncthreads();
    for (int c = 0; c < 8; ++c) {
        if (t == 0) {
            int p = c; float best = fabsf(aug[c][c]);
            for (int rr = c + 1; rr < 8; ++rr) {
                float v = fabsf(aug[rr][c]);
                if (v > best) { best = v; p = rr; }
            }
            piv = p;
        }
        __syncthreads();
        const int p = piv;
        float myv = aug[r][c2];
        __syncthreads();
        if (r == c)      aug[p][c2] = myv;
        else if (r == p) aug[c][c2] = myv;
        __syncthreads();
        const float pv = aug[c][c];
        __syncthreads();
        if (r == c) aug[r][c2] = aug[r][c2] / pv;
        __syncthreads();
        const float fac  = (r == c) ? 0.0f : aug[r][c];
        const float prow = aug[c][c2];
        __syncthreads();
        aug[r][c2] -= fac * prow;
        __syncthreads();
    }
    if (c2 >= 8) Qi[r * 8 + (c2 - 8)] = aug[r][c2];
}

__global__ __launch_bounds__(BT * NWAVE, 2)
void mlp_fused(const float* __restrict__ x, const float* __restrict__ Qi,
               const float* __restrict__ W0, const float* __restrict__ b0,
               const float* __restrict__ W1, const float* __restrict__ b1,
               const float* __restrict__ W2, const float* __restrict__ b2,
               const float* __restrict__ W3, const float* __restrict__ b3,
               const float* __restrict__ W4, const float* __restrict__ b4,
               float* __restrict__ out, int B)
{
    __shared__ float actA[NH * BT];
    __shared__ float actB[NH * BT];
    __shared__ float outP[NWAVE * NC * BT];

    const int lane = threadIdx.x & 63;
    const int wid  = __builtin_amdgcn_readfirstlane((int)(threadIdx.x >> 6));
    const int g    = blockIdx.x * BT + lane;
    const int j0   = wid * JB;

    float xr[NF];
    if (g < B) {
        const float4* xp = reinterpret_cast<const float4*>(x + (size_t)g * NF);
        float4 x0 = xp[0], x1 = xp[1];
        xr[0] = x0.x; xr[1] = x0.y; xr[2] = x0.z; xr[3] = x0.w;
        xr[4] = x1.x; xr[5] = x1.y; xr[6] = x1.z; xr[7] = x1.w;
    } else {
#pragma unroll
        for (int i = 0; i < NF; ++i) xr[i] = 0.0f;
    }
    float h[NF];
#pragma unroll
    for (int j = 0; j < NF; ++j) {
        float acc = b0[j];
#pragma unroll
        for (int k = 0; k < NF; ++k) acc = fmaf(W0[j * NF + k], xr[k], acc);
        h[j] = acc;
    }
    float tq[NF], u0[NF], u1[NF];
    const float h3 = h[3];
#pragma unroll
    for (int i = 0; i < NF; ++i) {
        float s = 0.0f;
#pragma unroll
        for (int k = 0; k < NF; ++k) s = fmaf(Qi[i * NF + k], h[k], s);
        tq[i] = s;
        u0[i] = fmaf(Qi[i * NF + 4], h3, Qi[i * NF + 5]);
        u1[i] = fmaf(Qi[i * NF + 6], h3, Qi[i * NF + 7]);
    }
    const float m00 = fmaf(h3, u0[4], u0[5]);
    const float m01 = fmaf(h3, u1[4], u1[5]);
    const float m10 = fmaf(h3, u0[6], u0[7]);
    const float m11 = fmaf(h3, u1[6], u1[7]);
    const float r0  = fmaf(h3, tq[4], tq[5]) - fmaf(h3, h[4], h[5]);
    const float r1  = fmaf(h3, tq[6], tq[7]) - fmaf(h3, h[6], h[7]);
    const float idet = 1.0f / (m00 * m11 - m01 * m10);
    const float nu0 = (m11 * r0 - m01 * r1) * idet;
    const float nu1 = (m00 * r1 - m10 * r0) * idet;
    float z[NF];
#pragma unroll
    for (int i = 0; i < NF; ++i) z[i] = tq[i] - u0[i] * nu0 - u1[i] * nu1;

#pragma unroll
    for (int jj = 0; jj < JB; ++jj) {
        const int j = j0 + jj;
        float acc = b1[j];
#pragma unroll
        for (int k = 0; k < NF; ++k) acc = fmaf(W1[j * NF + k], z[k], acc);
        actA[j * BT + lane] = fmaxf(acc, 0.0f);
    }
    __syncthreads();
    layer200(actA, actB, W2, b2, j0, lane);
    __syncthreads();
    layer200(actB, actA, W3, b3, j0, lane);
    __syncthreads();
    {
        float a[JB];
#pragma unroll
        for (int kk = 0; kk < JB; ++kk) a[kk] = actA[(j0 + kk) * BT + lane];
        float acc[NC];
#pragma unroll
        for (int o = 0; o < NC; ++o) acc[o] = 0.0f;
#pragma unroll
        for (int o = 0; o < NC; ++o) {
            const float* wr = W4 + o * NH + j0;
#pragma unroll
            for (int kk = 0; kk < JB; ++kk) acc[o] = fmaf(wr[kk], a[kk], acc[o]);
        }
#pragma unroll
        for (int o = 0; o < NC; ++o) outP[(wid * NC + o) * BT + lane] = acc[o];
    }
    __syncthreads();
    {
        float s = b4[wid];
#pragma unroll
        for (int w = 0; w < NWAVE; ++w) s += outP[(w * NC + wid) * BT + lane];
        if (g < B) out[(size_t)g * NC + wid] = s;
    }
}

// ===========================================================================
extern "C" void kernel_launch(void* const* d_in, const int* in_sizes, int n_in,
                              void* d_out, int out_size, void* d_ws, size_t ws_size,
                              hipStream_t stream)
{
    const float* x  = (const float*)d_in[0];
    const float* Q  = (const float*)d_in[1];
    const float* W0 = (const float*)d_in[2];
    const float* b0 = (const float*)d_in[3];
    const float* W1 = (const float*)d_in[4];
    const float* b1 = (const float*)d_in[5];
    const float* W2 = (const float*)d_in[6];
    const float* b2 = (const float*)d_in[7];
    const float* W3 = (const float*)d_in[8];
    const float* b3 = (const float*)d_in[9];
    const float* W4 = (const float*)d_in[10];
    const float* b4 = (const float*)d_in[11];
    float* out = (float*)d_out;

    const int B = in_sizes[0] / NF;

    if (ws_size >= WS_NEED) {
        hipLaunchKernelGGL(prep_kernel, dim3(23), dim3(256), 0, stream,
                           Q, W1, b1, W2, b2, W3, b3, W4, (char*)d_ws);
        hipLaunchKernelGGL(mlp_ns, dim3((B + M_BLK - 1) / M_BLK), dim3(128), 0, stream,
                           x, W0, b0, b4, (const char*)d_ws, out, B);
    } else {
        float* Qi = (float*)d_ws;
        hipLaunchKernelGGL(qinv_kernel, dim3(1), dim3(128), 0, stream, Q, Qi);
        hipLaunchKernelGGL(mlp_fused, dim3((B + BT - 1) / BT), dim3(BT * NWAVE), 0, stream,
                           x, Qi, W0, b0, W1, b1, W2, b2, W3, b3, W4, b4, out, B);
    }
}